// Round 9
// baseline (182.635 us; speedup 1.0000x reference)
//
#include <hip/hip_runtime.h>
#include <math.h>

#define Bn 16
#define Gn 2048
#define Cn 128
#define Kn 16
#define QB 32       // queries per block
#define AS 136      // A-tile row stride in bf16 elems: 272B = 17*16B (aligned, 2-way banks)

typedef __attribute__((ext_vector_type(8))) short bf16x8;
typedef __attribute__((ext_vector_type(4))) float f32x4;

__device__ __forceinline__ unsigned short f2bf(float x) {   // RNE fp32->bf16
    unsigned int u = __float_as_uint(x);
    unsigned int r = (u + 0x7fffu + ((u >> 16) & 1u)) >> 16;
    return (unsigned short)r;
}
__device__ __forceinline__ float bf2f(unsigned short h) {
    return __uint_as_float(((unsigned int)h) << 16);
}

__device__ __forceinline__ float med3f(float a, float b, float c) {
#if __has_builtin(__builtin_amdgcn_fmed3f)
    return __builtin_amdgcn_fmed3f(a, b, c);
#else
    return fmaxf(fminf(a, b), fminf(fmaxf(a, b), c));
#endif
}

// BIT-IDENTICAL in every phase (fp-consistent ranking incl. tie detection).
__device__ __forceinline__ float dist2(const float4 me, const float4 p) {
    float dot = fmaf(me.z, p.z, fmaf(me.y, p.y, me.x * p.x));
    return fmaf(-2.0f, dot, me.w + p.w);
}

__device__ __forceinline__ void ins16(float (&d)[16], float v) {
    float prev = d[0];
    d[0] = fminf(d[0], v);
    #pragma unroll
    for (int t = 1; t < 16; ++t) { float cur = d[t]; d[t] = med3f(v, prev, cur); prev = cur; }
}

// exact bitonic min-merge of sorted d[16] across the 16 lanes of a group.
// In-place: pairs (t,15-t) disjoint; both shfl reads precede writes.
__device__ __forceinline__ void merge16(float (&d)[16]) {
    #pragma unroll
    for (int m = 1; m < 16; m <<= 1) {
        #pragma unroll
        for (int t = 0; t < 8; ++t) {
            float sa = __shfl_xor(d[15 - t], m);    // partner's d[15-t]
            float sb = __shfl_xor(d[t], m);         // partner's d[t]
            d[t]      = fminf(d[t], sa);
            d[15 - t] = fminf(d[15 - t], sb);
        }
        #pragma unroll
        for (int k = 8; k; k >>= 1) {
            #pragma unroll
            for (int t = 0; t < 16; ++t)
                if (!(t & k)) {
                    float lo = fminf(d[t], d[t + k]);
                    float hi = fmaxf(d[t], d[t + k]);
                    d[t] = lo; d[t + k] = hi;
                }
        }
    }
}

__device__ __forceinline__ float gelu_exact(float x) {
    return 0.5f * x * (1.0f + erff(x * 0.70710678118654752440f));
}

// ---------------------------------------------------------------------------
// prep_w: W[k][n] fp32 -> Wt[n][k] split bf16 (hi/lo) in workspace.
// ws layout (ushorts): Wt1_hi[128*128] | Wt1_lo | Wt2_hi | Wt2_lo  (128 KB)
// ---------------------------------------------------------------------------
__global__ __launch_bounds__(256) void prep_w(const float* __restrict__ W1,
                                              const float* __restrict__ W2,
                                              unsigned short* __restrict__ ws) {
    int t = blockIdx.x * 256 + threadIdx.x;     // 0..16383 (grid 64)
    if (t < 16384) {
        int k = t >> 7, n = t & 127;
        float w = W1[t];
        unsigned short h = f2bf(w);
        unsigned short l = f2bf(w - bf2f(h));   // Dekker split: w-hi exact in fp32
        ws[n * 128 + k]          = h;
        ws[16384 + n * 128 + k]  = l;
        w = W2[t];
        h = f2bf(w);
        l = f2bf(w - bf2f(h));
        ws[32768 + n * 128 + k]  = h;
        ws[49152 + n * 128 + k]  = l;
    }
}

// ---------------------------------------------------------------------------
// Fully fused: KNN (sample->filter->select) + gather/L2-pool + MFMA MLP.
// 1024 blocks x 512 threads; b = x&15; chunk = x>>4 (0..63); 32 q/block.
// 16 lanes per query. INTERLEAVED point ownership: lane sub owns points
// {j*16+sub, j=0..127}. At step j the 16 subs read 256 contiguous bytes and
// all 4 query-groups of the wave read the SAME addresses (LDS broadcast):
// zero bank conflicts, zero per-point address VALU (imm-offset ds_read_b128).
// Survivors in 4x u32 register bitmask; decode h = (j<<4)|sub.
// T0 (phase A): per-lane top-2 over 32 sample pts, T0 = group-max(m2).
// Conservative proof: 16 lanes x 2 values <= T0 => >=32 sample values <= T0
// => T0 >= sample 16th >= exact T. Phase C recovers the exact T.
// LDS 34816 B -> 4 blocks/CU by LDS. No min-waves bound (R4/R6: forcing it
// makes LLVM split the unified file 32/32 and spill to scratch).
// MLP: split-bf16 MFMA 16x16x32 (Ahi*Bhi + Ahi*Blo + Alo*Bhi, err ~2^-17).
// ---------------------------------------------------------------------------
__global__ __launch_bounds__(512) void fused_kernel(const float* __restrict__ xyz,
                                                    const float* __restrict__ feat,
                                                    const float* __restrict__ b1,
                                                    const float* __restrict__ b2,
                                                    const unsigned short* __restrict__ wt,
                                                    float* __restrict__ out) {
    __shared__ __align__(16) float smem0[8704];       // 34816 B
    float4* pts = reinterpret_cast<float4*>(smem0);   // [2048] xyz + |p|^2 (0..32768)
    unsigned short* Ahi = reinterpret_cast<unsigned short*>(smem0);  // [32][AS] 0..8704
    unsigned short* Alo = Ahi + QB * AS;                             // 8704..17408
    unsigned short* outb = reinterpret_cast<unsigned short*>(smem0) + 16384;  // byte 32768, [32][16]
    unsigned short* tieb = outb + QB * 16;                                    // byte 33792, [32][16]

    const int x     = blockIdx.x;
    const int b     = x & 15;
    const int chunk = x >> 4;                       // 0..63
    const int tid   = threadIdx.x;                  // 0..511
    const int lane  = tid & 63;
    const int w     = tid >> 6;                     // 0..7
    const int sub   = lane & 15;                    // lane within 16-lane group
    const int qg    = lane >> 4;                    // query group within wave (0..3)
    const int q     = w * 4 + qg;                   // 0..31
    const int g     = chunk * QB + q;

    // ---- stage xyz + |p|^2
    const float* xb = xyz + (size_t)b * Gn * 3;
    for (int i = tid; i < Gn; i += 512) {
        float px = xb[i * 3 + 0], py = xb[i * 3 + 1], pz = xb[i * 3 + 2];
        pts[i] = make_float4(px, py, pz, px * px + py * py + pz * pz);
    }
    __syncthreads();

    const float4 me = pts[g];

    // ---- phase A: per-lane top-2 over 32-sample (points 0..511) -> T0
    float m1 = INFINITY, m2 = INFINITY;
    #pragma unroll 8
    for (int j = 0; j < 32; ++j) {
        float v = dist2(me, pts[j * 16 + sub]);
        m2 = med3f(v, m1, m2);                      // exact 2nd-smallest update
        m1 = fminf(m1, v);
    }
    float T0 = m2;
    #pragma unroll
    for (int m = 1; m < 16; m <<= 1) T0 = fmaxf(T0, __shfl_xor(T0, m));

    // ---- phase B: filter scan -> register bitmask (bit j <-> point j*16+sub)
    unsigned mw[4];
    #pragma unroll
    for (int wd = 0; wd < 4; ++wd) {
        unsigned mm = 0;
        #pragma unroll 8
        for (int j = 0; j < 32; ++j) {
            float v = dist2(me, pts[(wd * 32 + j) * 16 + sub]);
            mm |= (v <= T0) ? (1u << j) : 0u;
        }
        mw[wd] = mm;
    }
    unsigned long long blo = mw[0] | ((unsigned long long)mw[1] << 32);
    unsigned long long bhi = mw[2] | ((unsigned long long)mw[3] << 32);

    // ---- phase C: exact top16 of survivors (own bits) -> exact T
    float d[16];
    #pragma unroll
    for (int t = 0; t < 16; ++t) d[t] = INFINITY;
    {
        unsigned long long m = blo;
        while (m) {
            int p = __builtin_ctzll(m); m &= m - 1;
            int h = (p << 4) | sub;
            ins16(d, dist2(me, pts[h]));
        }
        m = bhi;
        while (m) {
            int p = 64 + __builtin_ctzll(m); m &= m - 1;
            int h = (p << 4) | sub;
            ins16(d, dist2(me, pts[h]));
        }
    }
    merge16(d);
    const float T = d[15];

    // ---- phase D: emit index set (group-max rounds, INF padding; ballots)
    int myc = __popcll(blo) + __popcll(bhi);
    int mymax = myc;
    #pragma unroll
    for (int m = 1; m < 16; m <<= 1) {
        int o = __shfl_xor(mymax, m);
        mymax = (o > mymax) ? o : mymax;
    }
    const unsigned lowm = (1u << sub) - 1;
    const int shft = lane & 48;                     // group base bit
    int nl = 0, nt = 0;
    for (int i = 0; i < mymax; ++i) {
        int h = 0; float v = INFINITY;
        if ((blo | bhi) != 0ull) {
            int p;
            if (blo) { p = __builtin_ctzll(blo); blo &= blo - 1; }
            else     { p = 64 + __builtin_ctzll(bhi); bhi &= bhi - 1; }
            h = (p << 4) | sub;
            v = dist2(me, pts[h]);
        }
        bool pl = (v < T), pt = (v == T);
        unsigned long long ml = __ballot(pl);
        unsigned long long mt = __ballot(pt);
        unsigned gml = (unsigned)(ml >> shft) & 0xFFFFu;
        unsigned gmt = (unsigned)(mt >> shft) & 0xFFFFu;
        if (pl) outb[q * 16 + nl + __popc(gml & lowm)] = (unsigned short)h;  // nl_total <= 15
        if (pt) { int pp = nt + __popc(gmt & lowm); if (pp < 16) tieb[q * 16 + pp] = (unsigned short)h; }
        nl += __popc(gml);
        nt += __popc(gmt);
    }
    if (sub == 0) {
        int mfill = nl;                              // < 16
        int need  = 16 - mfill;
        int tc = (nt > 16) ? 16 : nt;
        for (int s = 0; s < need; ++s) {
            int best = 0x7fffffff, bp = -1;
            for (int u = 0; u < tc; ++u) {
                int vv = tieb[q * 16 + u];
                if (vv < best) { best = vv; bp = u; }
            }
            if (bp >= 0) { tieb[q * 16 + bp] = 0xFFFF; outb[q * 16 + mfill + s] = (unsigned short)best; }
        }
    }
    __syncthreads();                                 // pts dead; outb ready (above pts window)

    // ---- gather + L2 pool: half-wave per query, float4 lanes (512B coalesced)
    // 2-neighbor chunks; accumulation order = outb order (set is exact top-16).
    const float4* fb4 = (const float4*)(feat + (size_t)b * Gn * Cn);
    const int cl = lane & 31;
    #pragma unroll
    for (int pass = 0; pass < 2; ++pass) {
        int qq = w * 4 + pass * 2 + (lane >> 5);
        float4 a = make_float4(0.f, 0.f, 0.f, 0.f);
        #pragma unroll
        for (int qt = 0; qt < 8; ++qt) {
            int hs[2]; float4 f[2];
            #pragma unroll
            for (int k = 0; k < 2; ++k) hs[k] = outb[qq * 16 + qt * 2 + k];
            #pragma unroll
            for (int k = 0; k < 2; ++k) f[k] = fb4[(size_t)hs[k] * 32 + cl];
            #pragma unroll
            for (int k = 0; k < 2; ++k) {
                a.x = fmaf(f[k].x, f[k].x, a.x);
                a.y = fmaf(f[k].y, f[k].y, a.y);
                a.z = fmaf(f[k].z, f[k].z, a.z);
                a.w = fmaf(f[k].w, f[k].w, a.w);
            }
        }
        float r0 = sqrtf(a.x), r1 = sqrtf(a.y), r2 = sqrtf(a.z), r3 = sqrtf(a.w);
        unsigned short h0 = f2bf(r0), h1 = f2bf(r1), h2 = f2bf(r2), h3 = f2bf(r3);
        ushort4 hv = make_ushort4(h0, h1, h2, h3);
        ushort4 lv = make_ushort4(f2bf(r0 - bf2f(h0)), f2bf(r1 - bf2f(h1)),
                                  f2bf(r2 - bf2f(h2)), f2bf(r3 - bf2f(h3)));
        *(ushort4*)&Ahi[qq * AS + cl * 4] = hv;
        *(ushort4*)&Alo[qq * AS + cl * 4] = lv;
    }
    __syncthreads();

    // ---- MLP via split-bf16 MFMA ------------------------------------------
    // wave w: rows rowg..rowg+15 (rowg=(w&1)*16), cols colg0..colg0+31
    // A-frag: lane l -> A[rowg+(l&15)][kk + (l>>4)*8 + j]  (contiguous bf16x8)
    // B-frag: lane l -> Wt[colg0+cb*16+(l&15)][kk + (l>>4)*8 + j] (contiguous)
    // C/D:    lane l, reg r -> C[(l>>4)*4 + r][l&15]   (m89-verified)
    const int l15  = lane & 15;
    const int kofs = (lane >> 4) * 8;
    const int rowg = (w & 1) * 16;
    const int colg0 = (w >> 1) * 32;
    const unsigned short* wt1h = wt;            // +16384: lo; +32768: W2 hi; +49152: W2 lo
    f32x4 acc[2];

    // ---- layer 1: h = gelu(pooled @ W1 + b1)
    #pragma unroll
    for (int cb = 0; cb < 2; ++cb) {
        float bv = b1[colg0 + cb * 16 + l15];
        acc[cb] = (f32x4){bv, bv, bv, bv};
    }
    #pragma unroll
    for (int kk = 0; kk < 128; kk += 32) {
        bf16x8 ah = *(const bf16x8*)&Ahi[rowg * AS + l15 * AS + kk + kofs];
        bf16x8 al = *(const bf16x8*)&Alo[rowg * AS + l15 * AS + kk + kofs];
        #pragma unroll
        for (int cb = 0; cb < 2; ++cb) {
            const unsigned short* wp = wt1h + (size_t)(colg0 + cb * 16 + l15) * 128 + kk + kofs;
            bf16x8 bh = *(const bf16x8*)wp;
            bf16x8 bl = *(const bf16x8*)(wp + 16384);
            acc[cb] = __builtin_amdgcn_mfma_f32_16x16x32_bf16(ah, bh, acc[cb], 0, 0, 0);
            acc[cb] = __builtin_amdgcn_mfma_f32_16x16x32_bf16(ah, bl, acc[cb], 0, 0, 0);
            acc[cb] = __builtin_amdgcn_mfma_f32_16x16x32_bf16(al, bh, acc[cb], 0, 0, 0);
        }
    }
    __syncthreads();                            // all layer-1 A reads done
    #pragma unroll
    for (int cb = 0; cb < 2; ++cb) {
        #pragma unroll
        for (int r = 0; r < 4; ++r) {
            float gv = gelu_exact(acc[cb][r]);
            unsigned short h = f2bf(gv);
            int row = rowg + (lane >> 4) * 4 + r;
            int col = colg0 + cb * 16 + l15;
            Ahi[row * AS + col] = h;
            Alo[row * AS + col] = f2bf(gv - bf2f(h));
        }
    }
    __syncthreads();                            // h tile complete

    // ---- layer 2: out = h @ W2 + b2
    #pragma unroll
    for (int cb = 0; cb < 2; ++cb) {
        float bv = b2[colg0 + cb * 16 + l15];
        acc[cb] = (f32x4){bv, bv, bv, bv};
    }
    #pragma unroll
    for (int kk = 0; kk < 128; kk += 32) {
        bf16x8 ah = *(const bf16x8*)&Ahi[rowg * AS + l15 * AS + kk + kofs];
        bf16x8 al = *(const bf16x8*)&Alo[rowg * AS + l15 * AS + kk + kofs];
        #pragma unroll
        for (int cb = 0; cb < 2; ++cb) {
            const unsigned short* wp = wt1h + 32768 + (size_t)(colg0 + cb * 16 + l15) * 128 + kk + kofs;
            bf16x8 bh = *(const bf16x8*)wp;
            bf16x8 bl = *(const bf16x8*)(wp + 16384);
            acc[cb] = __builtin_amdgcn_mfma_f32_16x16x32_bf16(ah, bh, acc[cb], 0, 0, 0);
            acc[cb] = __builtin_amdgcn_mfma_f32_16x16x32_bf16(ah, bl, acc[cb], 0, 0, 0);
            acc[cb] = __builtin_amdgcn_mfma_f32_16x16x32_bf16(al, bh, acc[cb], 0, 0, 0);
        }
    }
    // ---- store: lanes cover 16 consecutive cols (64B segments x 4 row-groups)
    const size_t orow0 = (size_t)b * Gn + (size_t)chunk * QB + rowg + (lane >> 4) * 4;
    #pragma unroll
    for (int cb = 0; cb < 2; ++cb) {
        #pragma unroll
        for (int r = 0; r < 4; ++r) {
            out[(orow0 + r) * Cn + colg0 + cb * 16 + l15] = acc[cb][r];
        }
    }
}

// ---------------------------------------------------------------------------
extern "C" void kernel_launch(void* const* d_in, const int* in_sizes, int n_in,
                              void* d_out, int out_size, void* d_ws, size_t ws_size,
                              hipStream_t stream) {
    const float* xyz  = (const float*)d_in[0];
    const float* feat = (const float*)d_in[1];
    const float* W1   = (const float*)d_in[2];
    const float* b1   = (const float*)d_in[3];
    const float* W2   = (const float*)d_in[4];
    const float* b2   = (const float*)d_in[5];
    float* out = (float*)d_out;
    unsigned short* wt = (unsigned short*)d_ws;    // 128 KB: Wt1 hi/lo, Wt2 hi/lo

    prep_w<<<64, 256, 0, stream>>>(W1, W2, wt);
    fused_kernel<<<1024, 512, 0, stream>>>(xyz, feat, b1, b2, wt, out);
}

// Round 10
// 155.911 us; speedup vs baseline: 1.1714x; 1.1714x over previous
//
#include <hip/hip_runtime.h>
#include <math.h>

#define Bn 16
#define Gn 2048
#define Cn 128
#define Kn 16
#define QB 32       // queries per block
#define AS 136      // A-tile row stride in bf16 elems: 272B = 17*16B (aligned, 2-way banks)

typedef __attribute__((ext_vector_type(8))) short bf16x8;
typedef __attribute__((ext_vector_type(4))) float f32x4;

__device__ __forceinline__ unsigned short f2bf(float x) {   // RNE fp32->bf16
    unsigned int u = __float_as_uint(x);
    unsigned int r = (u + 0x7fffu + ((u >> 16) & 1u)) >> 16;
    return (unsigned short)r;
}
__device__ __forceinline__ float bf2f(unsigned short h) {
    return __uint_as_float(((unsigned int)h) << 16);
}

__device__ __forceinline__ float med3f(float a, float b, float c) {
#if __has_builtin(__builtin_amdgcn_fmed3f)
    return __builtin_amdgcn_fmed3f(a, b, c);
#else
    return fmaxf(fminf(a, b), fminf(fmaxf(a, b), c));
#endif
}

// BIT-IDENTICAL in every phase (fp-consistent ranking incl. tie detection).
__device__ __forceinline__ float dist2(const float4 me, const float4 p) {
    float dot = fmaf(me.z, p.z, fmaf(me.y, p.y, me.x * p.x));
    return fmaf(-2.0f, dot, me.w + p.w);
}

__device__ __forceinline__ void ins16(float (&d)[16], float v) {
    float prev = d[0];
    d[0] = fminf(d[0], v);
    #pragma unroll
    for (int t = 1; t < 16; ++t) { float cur = d[t]; d[t] = med3f(v, prev, cur); prev = cur; }
}

// exact bitonic min-merge of sorted d[16] across the 16 lanes of a group.
// In-place: pairs (t,15-t) disjoint; both shfl reads precede writes.
__device__ __forceinline__ void merge16(float (&d)[16]) {
    #pragma unroll
    for (int m = 1; m < 16; m <<= 1) {
        #pragma unroll
        for (int t = 0; t < 8; ++t) {
            float sa = __shfl_xor(d[15 - t], m);    // partner's d[15-t]
            float sb = __shfl_xor(d[t], m);         // partner's d[t]
            d[t]      = fminf(d[t], sa);
            d[15 - t] = fminf(d[15 - t], sb);
        }
        #pragma unroll
        for (int k = 8; k; k >>= 1) {
            #pragma unroll
            for (int t = 0; t < 16; ++t)
                if (!(t & k)) {
                    float lo = fminf(d[t], d[t + k]);
                    float hi = fmaxf(d[t], d[t + k]);
                    d[t] = lo; d[t + k] = hi;
                }
        }
    }
}

__device__ __forceinline__ float gelu_exact(float x) {
    return 0.5f * x * (1.0f + erff(x * 0.70710678118654752440f));
}

// ---------------------------------------------------------------------------
// prep_w: W[k][n] fp32 -> Wt[n][k] split bf16 (hi/lo) in workspace.
// ws layout (ushorts): Wt1_hi[128*128] | Wt1_lo | Wt2_hi | Wt2_lo  (128 KB)
// ---------------------------------------------------------------------------
__global__ __launch_bounds__(256) void prep_w(const float* __restrict__ W1,
                                              const float* __restrict__ W2,
                                              unsigned short* __restrict__ ws) {
    int t = blockIdx.x * 256 + threadIdx.x;     // 0..16383 (grid 64)
    if (t < 16384) {
        int k = t >> 7, n = t & 127;
        float w = W1[t];
        unsigned short h = f2bf(w);
        unsigned short l = f2bf(w - bf2f(h));   // Dekker split: w-hi exact in fp32
        ws[n * 128 + k]          = h;
        ws[16384 + n * 128 + k]  = l;
        w = W2[t];
        h = f2bf(w);
        l = f2bf(w - bf2f(h));
        ws[32768 + n * 128 + k]  = h;
        ws[49152 + n * 128 + k]  = l;
    }
}

// ---------------------------------------------------------------------------
// Fully fused: KNN (sample->filter->select) + gather/L2-pool + MFMA MLP.
// 1024 blocks x 512 threads; b = x&15; chunk = x>>4 (0..63); 32 q/block.
// 16 lanes per query. INTERLEAVED point ownership (R9, validated: bank
// conflicts 5.2M->0.5M): lane sub owns points {j*16+sub}. At step j the 16
// subs read 256 contiguous bytes, broadcast across the 4 query groups:
// no conflicts, no per-point address VALU. Decode h = (j<<4)|sub.
// T0 (phase A): EXACT 16th of the 512-point sample (pts 0..511) via
// ins16 + merge16 — restored from R7 (R9 lesson: cheap max-of-lane-top2 T0
// has effective rank ~32-50, survivor count 2-4x, phases C/D dominate).
// Sample points are phase-B word 0 => survivor bits cover them => C exact.
// LDS 34816 B -> 4 blocks/CU by LDS. No min-waves bound (R4/R6: forcing it
// makes LLVM split the unified file 32/32 and spill to scratch).
// MLP: split-bf16 MFMA 16x16x32 (Ahi*Bhi + Ahi*Blo + Alo*Bhi, err ~2^-17).
// ---------------------------------------------------------------------------
__global__ __launch_bounds__(512) void fused_kernel(const float* __restrict__ xyz,
                                                    const float* __restrict__ feat,
                                                    const float* __restrict__ b1,
                                                    const float* __restrict__ b2,
                                                    const unsigned short* __restrict__ wt,
                                                    float* __restrict__ out) {
    __shared__ __align__(16) float smem0[8704];       // 34816 B
    float4* pts = reinterpret_cast<float4*>(smem0);   // [2048] xyz + |p|^2 (0..32768)
    unsigned short* Ahi = reinterpret_cast<unsigned short*>(smem0);  // [32][AS] 0..8704
    unsigned short* Alo = Ahi + QB * AS;                             // 8704..17408
    unsigned short* outb = reinterpret_cast<unsigned short*>(smem0) + 16384;  // byte 32768, [32][16]
    unsigned short* tieb = outb + QB * 16;                                    // byte 33792, [32][16]

    const int x     = blockIdx.x;
    const int b     = x & 15;
    const int chunk = x >> 4;                       // 0..63
    const int tid   = threadIdx.x;                  // 0..511
    const int lane  = tid & 63;
    const int w     = tid >> 6;                     // 0..7
    const int sub   = lane & 15;                    // lane within 16-lane group
    const int qg    = lane >> 4;                    // query group within wave (0..3)
    const int q     = w * 4 + qg;                   // 0..31
    const int g     = chunk * QB + q;

    // ---- stage xyz + |p|^2
    const float* xb = xyz + (size_t)b * Gn * 3;
    for (int i = tid; i < Gn; i += 512) {
        float px = xb[i * 3 + 0], py = xb[i * 3 + 1], pz = xb[i * 3 + 2];
        pts[i] = make_float4(px, py, pz, px * px + py * py + pz * pz);
    }
    __syncthreads();

    const float4 me = pts[g];

    // ---- phase A: EXACT top16 of 512-sample (points 0..511) -> T0
    float d[16];
    #pragma unroll
    for (int t = 0; t < 16; ++t) d[t] = INFINITY;
    #pragma unroll 4
    for (int j = 0; j < 32; ++j) {
        ins16(d, dist2(me, pts[j * 16 + sub]));
    }
    merge16(d);
    const float T0 = d[15];

    // ---- phase B: filter scan -> register bitmask (bit j <-> point j*16+sub)
    unsigned mw[4];
    #pragma unroll
    for (int wd = 0; wd < 4; ++wd) {
        unsigned mm = 0;
        #pragma unroll 8
        for (int j = 0; j < 32; ++j) {
            float v = dist2(me, pts[(wd * 32 + j) * 16 + sub]);
            mm |= (v <= T0) ? (1u << j) : 0u;
        }
        mw[wd] = mm;
    }
    unsigned long long blo = mw[0] | ((unsigned long long)mw[1] << 32);
    unsigned long long bhi = mw[2] | ((unsigned long long)mw[3] << 32);

    // ---- phase C: exact top16 of survivors (own bits) -> exact T
    #pragma unroll
    for (int t = 0; t < 16; ++t) d[t] = INFINITY;
    {
        unsigned long long m = blo;
        while (m) {
            int p = __builtin_ctzll(m); m &= m - 1;
            int h = (p << 4) | sub;
            ins16(d, dist2(me, pts[h]));
        }
        m = bhi;
        while (m) {
            int p = 64 + __builtin_ctzll(m); m &= m - 1;
            int h = (p << 4) | sub;
            ins16(d, dist2(me, pts[h]));
        }
    }
    merge16(d);
    const float T = d[15];

    // ---- phase D: emit index set (group-max rounds, INF padding; ballots)
    int myc = __popcll(blo) + __popcll(bhi);
    int mymax = myc;
    #pragma unroll
    for (int m = 1; m < 16; m <<= 1) {
        int o = __shfl_xor(mymax, m);
        mymax = (o > mymax) ? o : mymax;
    }
    const unsigned lowm = (1u << sub) - 1;
    const int shft = lane & 48;                     // group base bit
    int nl = 0, nt = 0;
    for (int i = 0; i < mymax; ++i) {
        int h = 0; float v = INFINITY;
        if ((blo | bhi) != 0ull) {
            int p;
            if (blo) { p = __builtin_ctzll(blo); blo &= blo - 1; }
            else     { p = 64 + __builtin_ctzll(bhi); bhi &= bhi - 1; }
            h = (p << 4) | sub;
            v = dist2(me, pts[h]);
        }
        bool pl = (v < T), pt = (v == T);
        unsigned long long ml = __ballot(pl);
        unsigned long long mt = __ballot(pt);
        unsigned gml = (unsigned)(ml >> shft) & 0xFFFFu;
        unsigned gmt = (unsigned)(mt >> shft) & 0xFFFFu;
        if (pl) outb[q * 16 + nl + __popc(gml & lowm)] = (unsigned short)h;  // nl_total <= 15
        if (pt) { int pp = nt + __popc(gmt & lowm); if (pp < 16) tieb[q * 16 + pp] = (unsigned short)h; }
        nl += __popc(gml);
        nt += __popc(gmt);
    }
    if (sub == 0) {
        int mfill = nl;                              // < 16
        int need  = 16 - mfill;
        int tc = (nt > 16) ? 16 : nt;
        for (int s = 0; s < need; ++s) {
            int best = 0x7fffffff, bp = -1;
            for (int u = 0; u < tc; ++u) {
                int vv = tieb[q * 16 + u];
                if (vv < best) { best = vv; bp = u; }
            }
            if (bp >= 0) { tieb[q * 16 + bp] = 0xFFFF; outb[q * 16 + mfill + s] = (unsigned short)best; }
        }
    }
    __syncthreads();                                 // pts dead; outb ready (above pts window)

    // ---- gather + L2 pool: half-wave per query, float4 lanes (512B coalesced)
    // 2-neighbor chunks; accumulation order = outb order (set is exact top-16).
    const float4* fb4 = (const float4*)(feat + (size_t)b * Gn * Cn);
    const int cl = lane & 31;
    #pragma unroll
    for (int pass = 0; pass < 2; ++pass) {
        int qq = w * 4 + pass * 2 + (lane >> 5);
        float4 a = make_float4(0.f, 0.f, 0.f, 0.f);
        #pragma unroll
        for (int qt = 0; qt < 8; ++qt) {
            int hs[2]; float4 f[2];
            #pragma unroll
            for (int k = 0; k < 2; ++k) hs[k] = outb[qq * 16 + qt * 2 + k];
            #pragma unroll
            for (int k = 0; k < 2; ++k) f[k] = fb4[(size_t)hs[k] * 32 + cl];
            #pragma unroll
            for (int k = 0; k < 2; ++k) {
                a.x = fmaf(f[k].x, f[k].x, a.x);
                a.y = fmaf(f[k].y, f[k].y, a.y);
                a.z = fmaf(f[k].z, f[k].z, a.z);
                a.w = fmaf(f[k].w, f[k].w, a.w);
            }
        }
        float r0 = sqrtf(a.x), r1 = sqrtf(a.y), r2 = sqrtf(a.z), r3 = sqrtf(a.w);
        unsigned short h0 = f2bf(r0), h1 = f2bf(r1), h2 = f2bf(r2), h3 = f2bf(r3);
        ushort4 hv = make_ushort4(h0, h1, h2, h3);
        ushort4 lv = make_ushort4(f2bf(r0 - bf2f(h0)), f2bf(r1 - bf2f(h1)),
                                  f2bf(r2 - bf2f(h2)), f2bf(r3 - bf2f(h3)));
        *(ushort4*)&Ahi[qq * AS + cl * 4] = hv;
        *(ushort4*)&Alo[qq * AS + cl * 4] = lv;
    }
    __syncthreads();

    // ---- MLP via split-bf16 MFMA ------------------------------------------
    // wave w: rows rowg..rowg+15 (rowg=(w&1)*16), cols colg0..colg0+31
    // A-frag: lane l -> A[rowg+(l&15)][kk + (l>>4)*8 + j]  (contiguous bf16x8)
    // B-frag: lane l -> Wt[colg0+cb*16+(l&15)][kk + (l>>4)*8 + j] (contiguous)
    // C/D:    lane l, reg r -> C[(l>>4)*4 + r][l&15]   (m89-verified)
    const int l15  = lane & 15;
    const int kofs = (lane >> 4) * 8;
    const int rowg = (w & 1) * 16;
    const int colg0 = (w >> 1) * 32;
    const unsigned short* wt1h = wt;            // +16384: lo; +32768: W2 hi; +49152: W2 lo
    f32x4 acc[2];

    // ---- layer 1: h = gelu(pooled @ W1 + b1)
    #pragma unroll
    for (int cb = 0; cb < 2; ++cb) {
        float bv = b1[colg0 + cb * 16 + l15];
        acc[cb] = (f32x4){bv, bv, bv, bv};
    }
    #pragma unroll
    for (int kk = 0; kk < 128; kk += 32) {
        bf16x8 ah = *(const bf16x8*)&Ahi[rowg * AS + l15 * AS + kk + kofs];
        bf16x8 al = *(const bf16x8*)&Alo[rowg * AS + l15 * AS + kk + kofs];
        #pragma unroll
        for (int cb = 0; cb < 2; ++cb) {
            const unsigned short* wp = wt1h + (size_t)(colg0 + cb * 16 + l15) * 128 + kk + kofs;
            bf16x8 bh = *(const bf16x8*)wp;
            bf16x8 bl = *(const bf16x8*)(wp + 16384);
            acc[cb] = __builtin_amdgcn_mfma_f32_16x16x32_bf16(ah, bh, acc[cb], 0, 0, 0);
            acc[cb] = __builtin_amdgcn_mfma_f32_16x16x32_bf16(ah, bl, acc[cb], 0, 0, 0);
            acc[cb] = __builtin_amdgcn_mfma_f32_16x16x32_bf16(al, bh, acc[cb], 0, 0, 0);
        }
    }
    __syncthreads();                            // all layer-1 A reads done
    #pragma unroll
    for (int cb = 0; cb < 2; ++cb) {
        #pragma unroll
        for (int r = 0; r < 4; ++r) {
            float gv = gelu_exact(acc[cb][r]);
            unsigned short h = f2bf(gv);
            int row = rowg + (lane >> 4) * 4 + r;
            int col = colg0 + cb * 16 + l15;
            Ahi[row * AS + col] = h;
            Alo[row * AS + col] = f2bf(gv - bf2f(h));
        }
    }
    __syncthreads();                            // h tile complete

    // ---- layer 2: out = h @ W2 + b2
    #pragma unroll
    for (int cb = 0; cb < 2; ++cb) {
        float bv = b2[colg0 + cb * 16 + l15];
        acc[cb] = (f32x4){bv, bv, bv, bv};
    }
    #pragma unroll
    for (int kk = 0; kk < 128; kk += 32) {
        bf16x8 ah = *(const bf16x8*)&Ahi[rowg * AS + l15 * AS + kk + kofs];
        bf16x8 al = *(const bf16x8*)&Alo[rowg * AS + l15 * AS + kk + kofs];
        #pragma unroll
        for (int cb = 0; cb < 2; ++cb) {
            const unsigned short* wp = wt1h + 32768 + (size_t)(colg0 + cb * 16 + l15) * 128 + kk + kofs;
            bf16x8 bh = *(const bf16x8*)wp;
            bf16x8 bl = *(const bf16x8*)(wp + 16384);
            acc[cb] = __builtin_amdgcn_mfma_f32_16x16x32_bf16(ah, bh, acc[cb], 0, 0, 0);
            acc[cb] = __builtin_amdgcn_mfma_f32_16x16x32_bf16(ah, bl, acc[cb], 0, 0, 0);
            acc[cb] = __builtin_amdgcn_mfma_f32_16x16x32_bf16(al, bh, acc[cb], 0, 0, 0);
        }
    }
    // ---- store: lanes cover 16 consecutive cols (64B segments x 4 row-groups)
    const size_t orow0 = (size_t)b * Gn + (size_t)chunk * QB + rowg + (lane >> 4) * 4;
    #pragma unroll
    for (int cb = 0; cb < 2; ++cb) {
        #pragma unroll
        for (int r = 0; r < 4; ++r) {
            out[(orow0 + r) * Cn + colg0 + cb * 16 + l15] = acc[cb][r];
        }
    }
}

// ---------------------------------------------------------------------------
extern "C" void kernel_launch(void* const* d_in, const int* in_sizes, int n_in,
                              void* d_out, int out_size, void* d_ws, size_t ws_size,
                              hipStream_t stream) {
    const float* xyz  = (const float*)d_in[0];
    const float* feat = (const float*)d_in[1];
    const float* W1   = (const float*)d_in[2];
    const float* b1   = (const float*)d_in[3];
    const float* W2   = (const float*)d_in[4];
    const float* b2   = (const float*)d_in[5];
    float* out = (float*)d_out;
    unsigned short* wt = (unsigned short*)d_ws;    // 128 KB: Wt1 hi/lo, Wt2 hi/lo

    prep_w<<<64, 256, 0, stream>>>(W1, W2, wt);
    fused_kernel<<<1024, 512, 0, stream>>>(xyz, feat, b1, b2, wt, out);
}